// Round 1
// baseline (346.236 us; speedup 1.0000x reference)
//
#include <hip/hip_runtime.h>

// HeadC: fused grouped-projection (q,k,v) + causal softmax attention.
// B=4096, T=50, N_EMBED=600, HEAD_SIZE=100, CHUNK=6.
// One block per batch element; everything after reading x stays in LDS.

#define BATCH 4096
#define TT 50
#define HH 100
#define CC 600
#define CHUNK 6

constexpr int NTHR = 256;
// score scale = C^-0.5 = 600^-0.5
__device__ __constant__ float kScale = 0.04082482904638630163f;

__global__ __launch_bounds__(NTHR, 2) void headc_fused(
    const float* __restrict__ x,
    const float* __restrict__ wq,
    const float* __restrict__ wk,
    const float* __restrict__ wv,
    float* __restrict__ out)
{
    // LDS budget: 3*2400 + 3*50*101*4 + 50*51*4 = 7200 + 60600 + 10200 = 78000 B
    // -> 2 blocks/CU (160 KiB), 8 waves/CU.
    __shared__ float s_wq[HH * CHUNK];
    __shared__ float s_wk[HH * CHUNK];
    __shared__ float s_wv[HH * CHUNK];
    __shared__ float s_q[TT][101];   // pad 101: stride mod 32 = 5 -> conflict-free k/q reads
    __shared__ float s_k[TT][101];
    __shared__ float s_v[TT][101];
    __shared__ float s_p[TT][TT + 1]; // scores then probabilities

    const int b = blockIdx.x;
    const int tid = threadIdx.x;
    const float* xb = x + (size_t)b * (TT * CC);

    // --- stage weights (600 floats each) ---
    for (int i = tid; i < HH * CHUNK; i += NTHR) {
        s_wq[i] = wq[i];
        s_wk[i] = wk[i];
        s_wv[i] = wv[i];
    }
    __syncthreads();

    // --- grouped projections: q/k/v[t][h] = dot6(x[b,t,h*6:], w*[h,:]) ---
    // 5000 (t,h) pairs; lane i reads 24 contiguous bytes -> wave reads 1536 B contiguous.
    for (int i = tid; i < TT * HH; i += NTHR) {
        const int t = i / HH;
        const int h = i - t * HH;
        const float* xp = xb + t * CC + h * CHUNK;
        const float2 x01 = *reinterpret_cast<const float2*>(xp);
        const float2 x23 = *reinterpret_cast<const float2*>(xp + 2);
        const float2 x45 = *reinterpret_cast<const float2*>(xp + 4);
        const float* wqp = s_wq + h * CHUNK;
        const float* wkp = s_wk + h * CHUNK;
        const float* wvp = s_wv + h * CHUNK;
        float aq = x01.x * wqp[0] + x01.y * wqp[1] + x23.x * wqp[2]
                 + x23.y * wqp[3] + x45.x * wqp[4] + x45.y * wqp[5];
        float ak = x01.x * wkp[0] + x01.y * wkp[1] + x23.x * wkp[2]
                 + x23.y * wkp[3] + x45.x * wkp[4] + x45.y * wkp[5];
        float av = x01.x * wvp[0] + x01.y * wvp[1] + x23.x * wvp[2]
                 + x23.y * wvp[3] + x45.x * wvp[4] + x45.y * wvp[5];
        s_q[t][h] = aq;
        s_k[t][h] = ak;
        s_v[t][h] = av;
    }
    __syncthreads();

    // --- scores: s_p[t][s] = scale * dot100(q[t], k[s]), causal (s<=t only) ---
    for (int i = tid; i < TT * TT; i += NTHR) {
        const int t = i / TT;
        const int s = i - t * TT;
        if (s <= t) {
            const float* qp = s_q[t];
            const float* kp = s_k[s];
            float acc = 0.f;
            #pragma unroll 4
            for (int h = 0; h < HH; ++h) acc += qp[h] * kp[h];
            s_p[t][s] = acc * kScale;
        }
    }
    __syncthreads();

    // --- softmax per row (row t has t+1 valid entries) ---
    if (tid < TT) {
        const int t = tid;
        float m = -1e30f;
        for (int s = 0; s <= t; ++s) m = fmaxf(m, s_p[t][s]);
        float sum = 0.f;
        for (int s = 0; s <= t; ++s) {
            const float e = __expf(s_p[t][s] - m);
            s_p[t][s] = e;
            sum += e;
        }
        const float inv = 1.f / sum;
        for (int s = 0; s <= t; ++s) s_p[t][s] *= inv;
    }
    __syncthreads();

    // --- PV: out[b,t,h] = sum_{s<=t} p[t][s] * v[s][h] ---
    float* ob = out + (size_t)b * (TT * HH);
    for (int i = tid; i < TT * HH; i += NTHR) {
        const int t = i / HH;
        const int h = i - t * HH;
        float acc = 0.f;
        for (int s = 0; s <= t; ++s) acc += s_p[t][s] * s_v[s][h];
        ob[i] = acc;  // i == t*HH + h, coalesced
    }
}

extern "C" void kernel_launch(void* const* d_in, const int* in_sizes, int n_in,
                              void* d_out, int out_size, void* d_ws, size_t ws_size,
                              hipStream_t stream) {
    const float* x  = (const float*)d_in[0];
    const float* wq = (const float*)d_in[1];
    const float* wk = (const float*)d_in[2];
    const float* wv = (const float*)d_in[3];
    float* out = (float*)d_out;
    headc_fused<<<dim3(BATCH), dim3(NTHR), 0, stream>>>(x, wq, wk, wv, out);
}

// Round 2
// 150.625 us; speedup vs baseline: 2.2987x; 2.2987x over previous
//
#include <hip/hip_runtime.h>

// HeadC fused: grouped 1x1-conv projections (q,k,v) + causal softmax attention.
// B=4096, T=50, N_EMBED=600, HEAD_SIZE=100, CHUNK=6. One block per batch.
// All LDS traffic is float4 (b128) with conflict-free strides; 2x2 register
// tiles for scores and PV; 50-lane vectorized softmax.

#define BATCH 4096
#define TT 50
#define HH 100
#define CC 600
#define CHUNK 6
#define PCOLS 52   // 52 dwords: stride mod 32 = 20 -> conflict-free b128 rows

constexpr int NTHR = 256;
constexpr float kScale = 0.04082482904638630163f;  // 600^-0.5

__device__ __forceinline__ float dot4(float4 a, float4 b) {
    return a.x * b.x + a.y * b.y + a.z * b.z + a.w * b.w;
}

__global__ __launch_bounds__(NTHR, 2) void headc_fused(
    const float* __restrict__ x,
    const float* __restrict__ wq,
    const float* __restrict__ wk,
    const float* __restrict__ wv,
    float* __restrict__ out)
{
    // Parity-split layouts: rows read by lane-varying float4 have stride
    // 100 dw (q,k) / 52 dw (vT,p) -> bank bases sweep all 32 banks.
    __shared__ __align__(16) float s_q[2][25][HH];      // [t&1][t>>1][h]  20000 B
    __shared__ __align__(16) float s_k[2][25][HH];      //                 20000 B
    __shared__ __align__(16) float s_vT[2][TT][PCOLS];  // [h&1][h>>1][t]  20800 B
    __shared__ __align__(16) float s_p[TT][PCOLS];      //                 10400 B
    // total 71200 B -> 2 blocks/CU, 8 waves/CU

    const int b = blockIdx.x;
    const int tid = threadIdx.x;
    const float* xb = x + (size_t)b * (TT * CC);

    // ---- phase 1: grouped projections, thread pins h, loops t ----
    {
        const int h = tid & 127;
        const int t0 = tid >> 7;  // parity of the t's this thread handles
        if (h < HH) {
            // weights -> registers (L2-resident after first blocks)
            const float2 wq01 = *(const float2*)(wq + h * CHUNK);
            const float2 wq23 = *(const float2*)(wq + h * CHUNK + 2);
            const float2 wq45 = *(const float2*)(wq + h * CHUNK + 4);
            const float2 wk01 = *(const float2*)(wk + h * CHUNK);
            const float2 wk23 = *(const float2*)(wk + h * CHUNK + 2);
            const float2 wk45 = *(const float2*)(wk + h * CHUNK + 4);
            const float2 wv01 = *(const float2*)(wv + h * CHUNK);
            const float2 wv23 = *(const float2*)(wv + h * CHUNK + 2);
            const float2 wv45 = *(const float2*)(wv + h * CHUNK + 4);
            for (int t = t0; t < TT; t += 2) {
                const float* xp = xb + t * CC + h * CHUNK;  // 24B/lane, contiguous across lanes
                const float2 x01 = *(const float2*)(xp);
                const float2 x23 = *(const float2*)(xp + 2);
                const float2 x45 = *(const float2*)(xp + 4);
                float aq = x01.x * wq01.x + x01.y * wq01.y + x23.x * wq23.x
                         + x23.y * wq23.y + x45.x * wq45.x + x45.y * wq45.y;
                float ak = x01.x * wk01.x + x01.y * wk01.y + x23.x * wk23.x
                         + x23.y * wk23.y + x45.x * wk45.x + x45.y * wk45.y;
                float av = x01.x * wv01.x + x01.y * wv01.y + x23.x * wv23.x
                         + x23.y * wv23.y + x45.x * wv45.x + x45.y * wv45.y;
                s_q[t0][t >> 1][h] = aq;
                s_k[t0][t >> 1][h] = ak;
                s_vT[h & 1][h >> 1][t] = av;
            }
        }
        // zero vT pad columns 50,51 so PV's last float4 chunk is 0*0 not 0*garbage
        if (tid < HH) {
            s_vT[tid & 1][tid >> 1][50] = 0.f;
            s_vT[tid & 1][tid >> 1][51] = 0.f;
        }
    }
    __syncthreads();

    // ---- phase 2: causal scores, 2x2 register tiles over lower triangle ----
    // 25x25 tile grid, 325 lower-tri tiles; t = {2tt,2tt+1}, s = {2ss,2ss+1}
    for (int j = tid; j < 325; j += NTHR) {
        int tt = (int)((sqrtf(8.f * (float)j + 1.f) - 1.f) * 0.5f);
        while ((tt + 1) * (tt + 2) / 2 <= j) ++tt;
        while (tt * (tt + 1) / 2 > j) --tt;
        const int ss = j - tt * (tt + 1) / 2;
        const float4* q0 = (const float4*)s_q[0][tt];
        const float4* q1 = (const float4*)s_q[1][tt];
        const float4* k0 = (const float4*)s_k[0][ss];
        const float4* k1 = (const float4*)s_k[1][ss];
        float a00 = 0.f, a01 = 0.f, a10 = 0.f, a11 = 0.f;
        #pragma unroll 5
        for (int c = 0; c < HH / 4; ++c) {
            const float4 qa = q0[c], qb = q1[c];
            const float4 ka = k0[c], kb = k1[c];
            a00 += dot4(qa, ka);
            a01 += dot4(qa, kb);
            a10 += dot4(qb, ka);
            a11 += dot4(qb, kb);
        }
        const int t0r = 2 * tt, t1r = 2 * tt + 1, s0 = 2 * ss;
        // (t0r, s0+1) may be acausal on diagonal tiles: softmax masks it.
        *(float2*)&s_p[t0r][s0] = make_float2(a00 * kScale, a01 * kScale);
        *(float2*)&s_p[t1r][s0] = make_float2(a10 * kScale, a11 * kScale);
    }
    __syncthreads();

    // ---- phase 3: softmax, one lane per row, float4 in registers ----
    if (tid < TT) {
        const int t = tid;
        const float4* pr = (const float4*)s_p[t];
        float4 vbuf[13];
        float m = -3.4e38f;
        #pragma unroll
        for (int c = 0; c < 13; ++c) {
            const float4 v = pr[c];   // stride 52 dw across lanes: conflict-free
            vbuf[c] = v;
            const int s = 4 * c;
            if (s     <= t) m = fmaxf(m, v.x);
            if (s + 1 <= t) m = fmaxf(m, v.y);
            if (s + 2 <= t) m = fmaxf(m, v.z);
            if (s + 3 <= t) m = fmaxf(m, v.w);
        }
        float sum = 0.f;
        #pragma unroll
        for (int c = 0; c < 13; ++c) {
            float4 v = vbuf[c];
            const int s = 4 * c;
            v.x = (s     <= t) ? __expf(v.x - m) : 0.f;
            v.y = (s + 1 <= t) ? __expf(v.y - m) : 0.f;
            v.z = (s + 2 <= t) ? __expf(v.z - m) : 0.f;
            v.w = (s + 3 <= t) ? __expf(v.w - m) : 0.f;
            sum += v.x + v.y + v.z + v.w;
            vbuf[c] = v;
        }
        const float inv = 1.f / sum;
        float4* pw = (float4*)s_p[t];
        #pragma unroll
        for (int c = 0; c < 13; ++c) {
            float4 v = vbuf[c];
            v.x *= inv; v.y *= inv; v.z *= inv; v.w *= inv;
            pw[c] = v;  // zeros for s>t -> PV needs no causal masking
        }
    }
    __syncthreads();

    // ---- phase 4: PV, 2x2 register tiles (t pair x h pair) ----
    float* ob = out + (size_t)b * (TT * HH);
    for (int i = tid; i < 25 * 50; i += NTHR) {
        const int hh = i % 50;        // fast dim -> conflict-free vT reads
        const int tp = i / 50;
        const int t0r = 2 * tp, t1r = t0r + 1;
        const int nch = (t1r >> 2) + 1;  // chunks covering s<=t1r (rest are 0)
        const float4* p0 = (const float4*)s_p[t0r];
        const float4* p1 = (const float4*)s_p[t1r];
        const float4* v0 = (const float4*)s_vT[0][hh];  // h = 2hh
        const float4* v1 = (const float4*)s_vT[1][hh];  // h = 2hh+1
        float a00 = 0.f, a01 = 0.f, a10 = 0.f, a11 = 0.f;
        #pragma unroll 4
        for (int c = 0; c < nch; ++c) {
            const float4 pa = p0[c], pb = p1[c];
            const float4 va = v0[c], vb = v1[c];
            a00 += dot4(pa, va);
            a01 += dot4(pa, vb);
            a10 += dot4(pb, va);
            a11 += dot4(pb, vb);
        }
        *(float2*)&ob[t0r * HH + 2 * hh] = make_float2(a00, a01);
        *(float2*)&ob[t1r * HH + 2 * hh] = make_float2(a10, a11);
    }
}

extern "C" void kernel_launch(void* const* d_in, const int* in_sizes, int n_in,
                              void* d_out, int out_size, void* d_ws, size_t ws_size,
                              hipStream_t stream) {
    const float* x  = (const float*)d_in[0];
    const float* wq = (const float*)d_in[1];
    const float* wk = (const float*)d_in[2];
    const float* wv = (const float*)d_in[3];
    float* out = (float*)d_out;
    headc_fused<<<dim3(BATCH), dim3(NTHR), 0, stream>>>(x, wq, wk, wv, out);
}

// Round 4
// 149.856 us; speedup vs baseline: 2.3105x; 1.0051x over previous
//
#include <hip/hip_runtime.h>

// HeadC fused: grouped 1x1-conv projections (q,k,v) + causal softmax attention.
// B=4096, T=50, N_EMBED=600, HEAD_SIZE=100, CHUNK=6. One block per batch.
// Scores and PV via mfma_f32_16x16x32_bf16; all LDS tiles bf16 with granule
// XOR swizzle (conflict-free b128 frag reads). 48.1 KB LDS -> 3 blocks/CU.
// R3 fix: tile loops stride by NWAVES=4 (was 8 -> half the tiles never ran).

#define BATCH 4096
#define TT 50
#define HH 100
#define CC 600

typedef __attribute__((ext_vector_type(8))) short short8;
typedef __attribute__((ext_vector_type(4))) float f32x4;
typedef unsigned short ushort_t;

constexpr int NTHR = 256;
constexpr int NWAVES = NTHR / 64;  // 4
constexpr float kScale = 0.04082482904638630163f;  // 600^-0.5 (folded into q)

// LDS layout (ushort units). Frag reads for q/k go up to "row 63" and spill
// into the next region: harmless (finite bf16 junk -> only discarded D rows
// t>=50 / masked D cols s>=50 are polluted).
//   s_q  @ 0      [50][128] bf16, stride 128, 16 granules/row, XOR row&7
//   s_k  @ 6400   [50][128]
//   s_vT @ 12800  [112][64]  (vT[h][t]), stride 64, 8 granules/row
//   s_p  @ 19968  [64][64]   (scores -> probabilities, in place)
constexpr int OQ = 0, OKk = 6400, OV = 12800, OP = 19968, LDS_US = 24064;

__device__ __forceinline__ ushort_t f2bf(float f) {  // RNE f32->bf16 (finite inputs)
    unsigned u = __float_as_uint(f);
    u += 0x7FFFu + ((u >> 16) & 1u);
    return (ushort_t)(u >> 16);
}
__device__ __forceinline__ float bf2f(ushort_t h) {
    return __uint_as_float(((unsigned)h) << 16);
}

__global__ __launch_bounds__(NTHR, 3) void headc_fused(
    const float* __restrict__ x,
    const float* __restrict__ wq,
    const float* __restrict__ wk,
    const float* __restrict__ wv,
    float* __restrict__ out)
{
    __shared__ __align__(16) ushort_t lds[LDS_US];

    const int b = blockIdx.x;
    const int tid = threadIdx.x;
    const float* xb = x + (size_t)b * (TT * CC);

    // ---- phase 0: zero q,k,vT (pad cols must be 0 for MFMA k-dim) ----
    for (int i = tid; i < 2496; i += NTHR) {
        short8 z = {0, 0, 0, 0, 0, 0, 0, 0};
        *reinterpret_cast<short8*>(lds + i * 8) = z;
    }
    __syncthreads();

    // ---- phase 1: projections. item = (t-octet, h-pair); 7*50 = 350 items.
    // Writes: q/k one b32 per t (bf16 pair, cols h0,h0+1); vT one b128 per h row.
    for (int j = tid; j < 350; j += NTHR) {
        const int oct = j / 50;
        const int hp  = j - oct * 50;
        const int h0  = hp * 2;
        const float4 wqa = *(const float4*)(wq + h0 * 6);
        const float4 wqb = *(const float4*)(wq + h0 * 6 + 4);
        const float4 wqc = *(const float4*)(wq + h0 * 6 + 8);
        const float4 wka = *(const float4*)(wk + h0 * 6);
        const float4 wkb = *(const float4*)(wk + h0 * 6 + 4);
        const float4 wkc = *(const float4*)(wk + h0 * 6 + 8);
        const float4 wva = *(const float4*)(wv + h0 * 6);
        const float4 wvb = *(const float4*)(wv + h0 * 6 + 4);
        const float4 wvc = *(const float4*)(wv + h0 * 6 + 8);
        short8 vp0 = {0,0,0,0,0,0,0,0};
        short8 vp1 = {0,0,0,0,0,0,0,0};
        #pragma unroll
        for (int r = 0; r < 8; ++r) {
            const int t = oct * 8 + r;
            if (t < TT) {
                const float* xp = xb + t * CC + h0 * 6;   // 48B/lane, coalesced
                const float4 xa = *(const float4*)xp;
                const float4 xm = *(const float4*)(xp + 4);
                const float4 xc = *(const float4*)(xp + 8);
                float q0 = xa.x*wqa.x + xa.y*wqa.y + xa.z*wqa.z + xa.w*wqa.w + xm.x*wqb.x + xm.y*wqb.y;
                float q1 = xm.z*wqb.z + xm.w*wqb.w + xc.x*wqc.x + xc.y*wqc.y + xc.z*wqc.z + xc.w*wqc.w;
                float k0 = xa.x*wka.x + xa.y*wka.y + xa.z*wka.z + xa.w*wka.w + xm.x*wkb.x + xm.y*wkb.y;
                float k1 = xm.z*wkb.z + xm.w*wkb.w + xc.x*wkc.x + xc.y*wkc.y + xc.z*wkc.z + xc.w*wkc.w;
                float v0 = xa.x*wva.x + xa.y*wva.y + xa.z*wva.z + xa.w*wva.w + xm.x*wvb.x + xm.y*wvb.y;
                float v1 = xm.z*wvb.z + xm.w*wvb.w + xc.x*wvc.x + xc.y*wvc.y + xc.z*wvc.z + xc.w*wvc.w;
                q0 *= kScale; q1 *= kScale;   // fold score scale into q
                const int qg = (((h0 >> 3) ^ (t & 7)) << 3) + (h0 & 7);
                *reinterpret_cast<unsigned*>(lds + OQ  + t * 128 + qg) =
                    (unsigned)f2bf(q0) | ((unsigned)f2bf(q1) << 16);
                *reinterpret_cast<unsigned*>(lds + OKk + t * 128 + qg) =
                    (unsigned)f2bf(k0) | ((unsigned)f2bf(k1) << 16);
                vp0[r] = (short)f2bf(v0);
                vp1[r] = (short)f2bf(v1);
            }
        }
        *reinterpret_cast<short8*>(lds + OV + h0 * 64 + ((oct ^ (h0 & 7)) << 3)) = vp0;
        *reinterpret_cast<short8*>(lds + OV + (h0 + 1) * 64 + ((oct ^ ((h0 + 1) & 7)) << 3)) = vp1;
    }
    __syncthreads();

    const int wv_ = tid >> 6;
    const int lane = tid & 63;
    const int l15 = lane & 15, l4 = lane >> 4;

    // ---- phase 2: scores S = Q*K^T via MFMA, 10 causal 16x16 tiles ----
    for (int p = wv_; p < 10; p += NWAVES) {
        const int tm = (p >= 6) ? 3 : (p >= 3) ? 2 : (p >= 1) ? 1 : 0;
        const int sn = p - tm * (tm + 1) / 2;
        f32x4 acc = {0.f, 0.f, 0.f, 0.f};
        const int ar = tm * 16 + l15;   // q row (may exceed 49: junk -> discarded rows)
        const int br = sn * 16 + l15;   // k row
        #pragma unroll
        for (int kk = 0; kk < 4; ++kk) {
            const int g = kk * 4 + l4;
            const short8 a  = *reinterpret_cast<const short8*>(lds + OQ  + ar * 128 + ((g ^ (ar & 7)) << 3));
            const short8 bb = *reinterpret_cast<const short8*>(lds + OKk + br * 128 + ((g ^ (br & 7)) << 3));
            acc = __builtin_amdgcn_mfma_f32_16x16x32_bf16(a, bb, acc, 0, 0, 0);
        }
        const int row0 = tm * 16 + l4 * 4;
        const int col = sn * 16 + l15;
        #pragma unroll
        for (int r = 0; r < 4; ++r) {
            const int row = row0 + r;
            lds[OP + row * 64 + (((col >> 3) ^ (row & 7)) << 3) + (col & 7)] = f2bf(acc[r]);
        }
    }
    __syncthreads();

    // ---- phase 3: softmax, one lane per row, in place in s_p ----
    if (tid < TT) {
        const int t = tid;
        float vv[64];
        float mx = -3.4e38f;
        #pragma unroll
        for (int g = 0; g < 8; ++g) {
            const short8 pk = *reinterpret_cast<const short8*>(lds + OP + t * 64 + ((g ^ (t & 7)) << 3));
            #pragma unroll
            for (int jj = 0; jj < 8; ++jj) {
                const int s = g * 8 + jj;
                const float f = bf2f((ushort_t)pk[jj]);
                vv[s] = f;
                mx = (s <= t) ? fmaxf(mx, f) : mx;   // junk beyond row masked pre-exp
            }
        }
        float sum = 0.f;
        #pragma unroll
        for (int s = 0; s < 64; ++s) {
            const float e = (s <= t) ? __expf(vv[s] - mx) : 0.f;
            vv[s] = e;
            sum += e;
        }
        const float inv = 1.f / sum;
        #pragma unroll
        for (int g = 0; g < 8; ++g) {
            short8 w;
            #pragma unroll
            for (int jj = 0; jj < 8; ++jj) w[jj] = (short)f2bf(vv[g * 8 + jj] * inv);
            *reinterpret_cast<short8*>(lds + OP + t * 64 + ((g ^ (t & 7)) << 3)) = w;
        }
    }
    __syncthreads();

    // ---- phase 4: O = P*V via MFMA, 4x7 tiles, K = 64 (P zeros past t) ----
    float* ob = out + (size_t)b * (TT * HH);
    for (int p = wv_; p < 28; p += NWAVES) {
        const int tm = p / 7, hn = p - tm * 7;
        f32x4 acc = {0.f, 0.f, 0.f, 0.f};
        const int ar = tm * 16 + l15;   // p row
        const int br = hn * 16 + l15;   // vT row (h)
        #pragma unroll
        for (int kk = 0; kk < 2; ++kk) {
            const int g = kk * 4 + l4;
            const short8 a  = *reinterpret_cast<const short8*>(lds + OP + ar * 64 + ((g ^ (ar & 7)) << 3));
            const short8 bb = *reinterpret_cast<const short8*>(lds + OV + br * 64 + ((g ^ (br & 7)) << 3));
            acc = __builtin_amdgcn_mfma_f32_16x16x32_bf16(a, bb, acc, 0, 0, 0);
        }
        const int h = hn * 16 + l15;
        const int t0 = tm * 16 + l4 * 4;
        if (h < HH) {
            #pragma unroll
            for (int r = 0; r < 4; ++r) {
                const int t = t0 + r;
                if (t < TT) ob[t * HH + h] = acc[r];
            }
        }
    }
}

extern "C" void kernel_launch(void* const* d_in, const int* in_sizes, int n_in,
                              void* d_out, int out_size, void* d_ws, size_t ws_size,
                              hipStream_t stream) {
    const float* x  = (const float*)d_in[0];
    const float* wq = (const float*)d_in[1];
    const float* wk = (const float*)d_in[2];
    const float* wv = (const float*)d_in[3];
    float* out = (float*)d_out;
    headc_fused<<<dim3(BATCH), dim3(NTHR), 0, stream>>>(x, wq, wk, wv, out);
}

// Round 5
// 132.759 us; speedup vs baseline: 2.6080x; 1.1288x over previous
//
#include <hip/hip_runtime.h>

// HeadC fused: grouped 1x1-conv projections (q,k,v) + causal softmax attention.
// B=4096, T=50, N_EMBED=600, HEAD_SIZE=100, CHUNK=6. One block per batch.
// Scores and PV via mfma_f32_16x16x32_bf16; LDS tiles bf16, granule XOR swizzle.
// R5: phase 1 restructured for memory-level parallelism — all 12 x-loads + 9
// weight-loads per item issued independently (register arrays, static idx)
// before any dependent compute. Items are (t-quad, h-pair): 650 items.

#define BATCH 4096
#define TT 50
#define HH 100
#define CC 600

typedef __attribute__((ext_vector_type(8))) short short8;
typedef __attribute__((ext_vector_type(4))) short short4v;
typedef __attribute__((ext_vector_type(4))) float f32x4;
typedef unsigned short ushort_t;

constexpr int NTHR = 256;
constexpr int NWAVES = NTHR / 64;  // 4
constexpr float kScale = 0.04082482904638630163f;  // 600^-0.5 (folded into q)

// LDS layout (ushort units). Frag reads spill into the next region: harmless
// (finite bf16 junk -> only discarded D rows / masked cols polluted).
//   s_q  @ 0      [50][128] bf16, 16 granules/row, XOR row&7
//   s_k  @ 6400   [50][128]
//   s_vT @ 12800  [112][64]  (vT[h][t])
//   s_p  @ 19968  [64][64]   (scores -> probabilities, in place)
constexpr int OQ = 0, OKk = 6400, OV = 12800, OP = 19968, LDS_US = 24064;

__device__ __forceinline__ ushort_t f2bf(float f) {  // RNE f32->bf16 (finite)
    unsigned u = __float_as_uint(f);
    u += 0x7FFFu + ((u >> 16) & 1u);
    return (ushort_t)(u >> 16);
}
__device__ __forceinline__ float bf2f(ushort_t h) {
    return __uint_as_float(((unsigned)h) << 16);
}

__global__ __launch_bounds__(NTHR, 3) void headc_fused(
    const float* __restrict__ x,
    const float* __restrict__ wq,
    const float* __restrict__ wk,
    const float* __restrict__ wv,
    float* __restrict__ out)
{
    __shared__ __align__(16) ushort_t lds[LDS_US];

    const int b = blockIdx.x;
    const int tid = threadIdx.x;
    const float* xb = x + (size_t)b * (TT * CC);

    // ---- phase 0: zero q,k,vT (pads must be 0 for MFMA K-dim) ----
    for (int i = tid; i < 2496; i += NTHR) {
        short8 z = {0, 0, 0, 0, 0, 0, 0, 0};
        *reinterpret_cast<short8*>(lds + i * 8) = z;
    }
    __syncthreads();

    // ---- phase 1: projections. item = (t-quad, h-pair); 13*50 = 650 items.
    for (int j = tid; j < 650; j += NTHR) {
        const int qd = j / 50;          // 0..12
        const int hp = j - qd * 50;
        const int h0 = hp * 2;
        const int tbase = qd * 4;

        // 12 independent x loads (clamped row for the t>=50 tail; discarded)
        float4 xr[4][3];
        #pragma unroll
        for (int r = 0; r < 4; ++r) {
            const int tc = (tbase + r < TT) ? (tbase + r) : (TT - 1);
            const float* xp = xb + tc * CC + h0 * 6;   // 48B/lane, coalesced
            xr[r][0] = *(const float4*)xp;
            xr[r][1] = *(const float4*)(xp + 4);
            xr[r][2] = *(const float4*)(xp + 8);
        }
        // 9 independent weight loads (L2-hot after first blocks)
        const float4 wqa = *(const float4*)(wq + h0 * 6);
        const float4 wqb = *(const float4*)(wq + h0 * 6 + 4);
        const float4 wqc = *(const float4*)(wq + h0 * 6 + 8);
        const float4 wka = *(const float4*)(wk + h0 * 6);
        const float4 wkb = *(const float4*)(wk + h0 * 6 + 4);
        const float4 wkc = *(const float4*)(wk + h0 * 6 + 8);
        const float4 wva = *(const float4*)(wv + h0 * 6);
        const float4 wvb = *(const float4*)(wv + h0 * 6 + 4);
        const float4 wvc = *(const float4*)(wv + h0 * 6 + 8);

        short4v vp0 = {0, 0, 0, 0};
        short4v vp1 = {0, 0, 0, 0};
        #pragma unroll
        for (int r = 0; r < 4; ++r) {
            const int t = tbase + r;
            const float4 xa = xr[r][0], xm = xr[r][1], xc = xr[r][2];
            float q0 = xa.x*wqa.x + xa.y*wqa.y + xa.z*wqa.z + xa.w*wqa.w + xm.x*wqb.x + xm.y*wqb.y;
            float q1 = xm.z*wqb.z + xm.w*wqb.w + xc.x*wqc.x + xc.y*wqc.y + xc.z*wqc.z + xc.w*wqc.w;
            float k0 = xa.x*wka.x + xa.y*wka.y + xa.z*wka.z + xa.w*wka.w + xm.x*wkb.x + xm.y*wkb.y;
            float k1 = xm.z*wkb.z + xm.w*wkb.w + xc.x*wkc.x + xc.y*wkc.y + xc.z*wkc.z + xc.w*wkc.w;
            float v0 = xa.x*wva.x + xa.y*wva.y + xa.z*wva.z + xa.w*wva.w + xm.x*wvb.x + xm.y*wvb.y;
            float v1 = xm.z*wvb.z + xm.w*wvb.w + xc.x*wvc.x + xc.y*wvc.y + xc.z*wvc.z + xc.w*wvc.w;
            q0 *= kScale; q1 *= kScale;   // fold score scale into q
            if (t < TT) {
                const int qg = (((h0 >> 3) ^ (t & 7)) << 3) + (h0 & 7);
                *reinterpret_cast<unsigned*>(lds + OQ  + t * 128 + qg) =
                    (unsigned)f2bf(q0) | ((unsigned)f2bf(q1) << 16);
                *reinterpret_cast<unsigned*>(lds + OKk + t * 128 + qg) =
                    (unsigned)f2bf(k0) | ((unsigned)f2bf(k1) << 16);
                vp0[r] = (short)f2bf(v0);
                vp1[r] = (short)f2bf(v1);
            }
        }
        // vT: half-granule (4 ushorts = 8B) per h row
        const int g = qd >> 1, half = (qd & 1) * 4;
        *reinterpret_cast<short4v*>(lds + OV + h0 * 64 + ((g ^ (h0 & 7)) << 3) + half) = vp0;
        *reinterpret_cast<short4v*>(lds + OV + (h0 + 1) * 64 + ((g ^ ((h0 + 1) & 7)) << 3) + half) = vp1;
    }
    __syncthreads();

    const int wv_ = tid >> 6;
    const int lane = tid & 63;
    const int l15 = lane & 15, l4 = lane >> 4;

    // ---- phase 2: scores S = Q*K^T via MFMA, 10 causal 16x16 tiles ----
    for (int p = wv_; p < 10; p += NWAVES) {
        const int tm = (p >= 6) ? 3 : (p >= 3) ? 2 : (p >= 1) ? 1 : 0;
        const int sn = p - tm * (tm + 1) / 2;
        f32x4 acc = {0.f, 0.f, 0.f, 0.f};
        const int ar = tm * 16 + l15;   // q row (>=50: junk -> discarded rows)
        const int br = sn * 16 + l15;   // k row
        #pragma unroll
        for (int kk = 0; kk < 4; ++kk) {
            const int g = kk * 4 + l4;
            const short8 a  = *reinterpret_cast<const short8*>(lds + OQ  + ar * 128 + ((g ^ (ar & 7)) << 3));
            const short8 bb = *reinterpret_cast<const short8*>(lds + OKk + br * 128 + ((g ^ (br & 7)) << 3));
            acc = __builtin_amdgcn_mfma_f32_16x16x32_bf16(a, bb, acc, 0, 0, 0);
        }
        const int row0 = tm * 16 + l4 * 4;
        const int col = sn * 16 + l15;
        #pragma unroll
        for (int r = 0; r < 4; ++r) {
            const int row = row0 + r;
            lds[OP + row * 64 + (((col >> 3) ^ (row & 7)) << 3) + (col & 7)] = f2bf(acc[r]);
        }
    }
    __syncthreads();

    // ---- phase 3: softmax, one lane per row, in place in s_p ----
    if (tid < TT) {
        const int t = tid;
        float vv[64];
        float mx = -3.4e38f;
        #pragma unroll
        for (int g = 0; g < 8; ++g) {
            const short8 pk = *reinterpret_cast<const short8*>(lds + OP + t * 64 + ((g ^ (t & 7)) << 3));
            #pragma unroll
            for (int jj = 0; jj < 8; ++jj) {
                const int s = g * 8 + jj;
                const float f = bf2f((ushort_t)pk[jj]);
                vv[s] = f;
                mx = (s <= t) ? fmaxf(mx, f) : mx;
            }
        }
        float sum = 0.f;
        #pragma unroll
        for (int s = 0; s < 64; ++s) {
            const float e = (s <= t) ? __expf(vv[s] - mx) : 0.f;
            vv[s] = e;
            sum += e;
        }
        const float inv = 1.f / sum;
        #pragma unroll
        for (int g = 0; g < 8; ++g) {
            short8 w;
            #pragma unroll
            for (int jj = 0; jj < 8; ++jj) w[jj] = (short)f2bf(vv[g * 8 + jj] * inv);
            *reinterpret_cast<short8*>(lds + OP + t * 64 + ((g ^ (t & 7)) << 3)) = w;
        }
    }
    __syncthreads();

    // ---- phase 4: O = P*V via MFMA, 4x7 tiles, K = 64 (P zeros past t) ----
    float* ob = out + (size_t)b * (TT * HH);
    for (int p = wv_; p < 28; p += NWAVES) {
        const int tm = p / 7, hn = p - tm * 7;
        f32x4 acc = {0.f, 0.f, 0.f, 0.f};
        const int ar = tm * 16 + l15;   // p row
        const int br = hn * 16 + l15;   // vT row (h)
        #pragma unroll
        for (int kk = 0; kk < 2; ++kk) {
            const int g = kk * 4 + l4;
            const short8 a  = *reinterpret_cast<const short8*>(lds + OP + ar * 64 + ((g ^ (ar & 7)) << 3));
            const short8 bb = *reinterpret_cast<const short8*>(lds + OV + br * 64 + ((g ^ (br & 7)) << 3));
            acc = __builtin_amdgcn_mfma_f32_16x16x32_bf16(a, bb, acc, 0, 0, 0);
        }
        const int h = hn * 16 + l15;
        const int t0 = tm * 16 + l4 * 4;
        if (h < HH) {
            #pragma unroll
            for (int r = 0; r < 4; ++r) {
                const int t = t0 + r;
                if (t < TT) ob[t * HH + h] = acc[r];
            }
        }
    }
}

extern "C" void kernel_launch(void* const* d_in, const int* in_sizes, int n_in,
                              void* d_out, int out_size, void* d_ws, size_t ws_size,
                              hipStream_t stream) {
    const float* x  = (const float*)d_in[0];
    const float* wq = (const float*)d_in[1];
    const float* wk = (const float*)d_in[2];
    const float* wv = (const float*)d_in[3];
    float* out = (float*)d_out;
    headc_fused<<<dim3(BATCH), dim3(NTHR), 0, stream>>>(x, wq, wk, wv, out);
}